// Round 7
// baseline (910.228 us; speedup 1.0000x reference)
//
#include <hip/hip_runtime.h>
#include <hip/hip_bf16.h>
#include <math.h>

#define N_NODES 10000
#define N_EDGES 160000
#define NBLK 512

typedef __attribute__((ext_vector_type(8))) short bf16x8;
typedef __attribute__((ext_vector_type(4))) float f32x4;
typedef __attribute__((ext_vector_type(4))) double f64x4;

static __device__ inline unsigned short f2b(float v) {
    __hip_bfloat16 b = __float2bfloat16(v);
    return *reinterpret_cast<unsigned short*>(&b);
}

// ---------------- pre: zero cnt+cntd+barrier (21760 ints) + transpose all three w2 ----------------
// w2t[i*1024 + o*32 + k] = w2[k*(din*32) + i*32 + o]
__global__ __launch_bounds__(256) void k_pre(const float* __restrict__ s0,
                                             const float* __restrict__ s1,
                                             const float* __restrict__ s2,
                                             float* __restrict__ t0,
                                             float* __restrict__ t1,
                                             float* __restrict__ t2,
                                             int* __restrict__ z) {
    int tid = blockIdx.x * 256 + threadIdx.x;
    if (tid < 21760) { z[tid] = 0; return; }
    int d = tid - 21760;
    if (d < 4096) {                            // layer 0, din=4
        int i = d >> 10, j = d & 1023, o = j >> 5, k = j & 31;
        t0[d] = s0[k * 128 + i * 32 + o];
    } else if (d < 4096 + 32768) {
        int q = d - 4096;
        int i = q >> 10, j = q & 1023, o = j >> 5, k = j & 31;
        t1[q] = s1[k * 1024 + i * 32 + o];
    } else if (d < 4096 + 65536) {
        int q = d - 4096 - 32768;
        int i = q >> 10, j = q & 1023, o = j >> 5, k = j & 31;
        t2[q] = s2[k * 1024 + i * 32 + o];
    }
}

// ---------------- manual grid barrier (512 co-resident blocks guaranteed by launch_bounds) --------
// Per-block flag stores (no same-address atomic contention); block 0 collects, flips gen.
__device__ __forceinline__ void grid_sync(int* flags, int* genp, int it) {
    __syncthreads();
    const int t = threadIdx.x;
    if (blockIdx.x == 0) {
        for (int b = t; b < NBLK; b += 256) {
            if (b == 0) continue;
            while (__hip_atomic_load(&flags[b], __ATOMIC_RELAXED, __HIP_MEMORY_SCOPE_AGENT) < it)
                __builtin_amdgcn_s_sleep(2);
        }
        __syncthreads();                       // all flags observed
        if (t == 0) {
            __threadfence();                   // acquire all blocks' data / release own
            __hip_atomic_store(genp, it, __ATOMIC_RELEASE, __HIP_MEMORY_SCOPE_AGENT);
        }
        __syncthreads();
    } else {
        if (t == 0) {
            __threadfence();                   // release this block's writes
            __hip_atomic_store(&flags[blockIdx.x], it, __ATOMIC_RELEASE, __HIP_MEMORY_SCOPE_AGENT);
            while (__hip_atomic_load(genp, __ATOMIC_RELAXED, __HIP_MEMORY_SCOPE_AGENT) < it)
                __builtin_amdgcn_s_sleep(2);
            __threadfence();                   // acquire
        }
        __syncthreads();
    }
}

// ---------------- phase bodies: VERBATIM round-6 kernels, parameterized by unit ----------------

// scan: exclusive scan of c[10000] -> o[10001], cu = o (one block's worth)
__device__ void scan_body(const int* __restrict__ c, int* __restrict__ o, int* __restrict__ cu,
                          char* smem) {
    int* part = (int*)smem;
    int t = threadIdx.x;
    int base = t * 40;
    int s = 0;
    for (int i = 0; i < 40; ++i) {
        int idx = base + i;
        if (idx < N_NODES) s += c[idx];
    }
    part[t] = s;
    __syncthreads();
    for (int d = 1; d < 256; d <<= 1) {
        int v = (t >= d) ? part[t - d] : 0;
        __syncthreads();
        part[t] += v;
        __syncthreads();
    }
    int run = part[t] - s;
    for (int i = 0; i < 40; ++i) {
        int idx = base + i;
        if (idx < N_NODES) {
            o[idx] = run;
            cu[idx] = run;
            run += c[idx];
        }
    }
    if (t == 255) o[N_NODES] = run;
    __syncthreads();
}

// G unit: 8 nodes starting at n0 (round-6 k_G body; fp64 gather, bf16 G, xb2+agg init)
template <int DIN, bool FIRST>
__device__ __forceinline__ void G_unit(int n0,
                                       const float* __restrict__ xin,
                                       const int* __restrict__ dst_off,
                                       const float* __restrict__ msgd,
                                       const float* __restrict__ w2t,
                                       const float* __restrict__ b2,
                                       const float* __restrict__ root,
                                       const float* __restrict__ bias,
                                       unsigned short* __restrict__ Gb,
                                       float* __restrict__ xb2,
                                       float* __restrict__ agg,
                                       char* smem) {
    const int t = threadIdx.x;
    float* xs = (float*)(smem + 8192);

    if constexpr (FIRST) {
        for (int idx = t; idx < 8 * DIN; idx += 256) {
            int m = idx / DIN, i = idx - m * DIN;
            xs[idx] = xin[(size_t)(n0 + m) * DIN + i];
        }
        __syncthreads();
    } else {
        f64x4* part = (f64x4*)smem;
        {
            int m = t >> 5, s = t & 31;        // 8 nodes x (8 groups x 4 slot-quarters)
            int g = s >> 2, quar = s & 3;
            int n = n0 + m;
            int jb = dst_off[n], je = dst_off[n + 1];
            f64x4 a0 = {0.0, 0.0, 0.0, 0.0}, a1 = {0.0, 0.0, 0.0, 0.0};
            int j = jb + quar;
            for (; j + 4 < je; j += 8) {
                f32x4 m0 = *(const f32x4*)(msgd + (size_t)j * 32 + g * 4);
                f32x4 m1 = *(const f32x4*)(msgd + (size_t)(j + 4) * 32 + g * 4);
                a0 += __builtin_convertvector(m0, f64x4);
                a1 += __builtin_convertvector(m1, f64x4);
            }
            if (j < je) {
                f32x4 m0 = *(const f32x4*)(msgd + (size_t)j * 32 + g * 4);
                a0 += __builtin_convertvector(m0, f64x4);
            }
            part[t] = a0 + a1;
        }
        __syncthreads();
        if (t < 64) {
            int m = t >> 3, g = t & 7;
            f64x4 v = part[m * 32 + g * 4] + part[m * 32 + g * 4 + 1] +
                      part[m * 32 + g * 4 + 2] + part[m * 32 + g * 4 + 3];
            const f32x4 xi = *(const f32x4*)(xin + (size_t)(n0 + m) * 32 + g * 4);
            v += __builtin_convertvector(xi, f64x4);
#pragma unroll
            for (int c = 0; c < 4; ++c) {
                float f = (float)v[c];
                xs[m * 32 + g * 4 + c] = f > 0.f ? f : 0.f;
            }
        }
        __syncthreads();
    }

    float acc[8][4];
#pragma unroll
    for (int m = 0; m < 8; ++m)
        acc[m][0] = acc[m][1] = acc[m][2] = acc[m][3] = 0.f;

#pragma unroll
    for (int i = 0; i < DIN; ++i) {
        const float4 w = *(const float4*)(w2t + i * 1024 + t * 4);
#pragma unroll
        for (int m = 0; m < 8; ++m) {
            float xv = xs[m * DIN + i];
            acc[m][0] += xv * w.x;
            acc[m][1] += xv * w.y;
            acc[m][2] += xv * w.z;
            acc[m][3] += xv * w.w;
        }
    }
#pragma unroll
    for (int m = 0; m < 8; ++m) {
        unsigned int p0 = (unsigned int)f2b(acc[m][0]) | ((unsigned int)f2b(acc[m][1]) << 16);
        unsigned int p1 = (unsigned int)f2b(acc[m][2]) | ((unsigned int)f2b(acc[m][3]) << 16);
        *(uint2*)(Gb + (size_t)(n0 + m) * 1024 + t * 4) = make_uint2(p0, p1);
    }

    {
        int m = t >> 5, o = t & 31;            // 8*32 = 256 = blockDim
        float ab = 0.f, ar = bias[o];
#pragma unroll
        for (int i = 0; i < DIN; ++i) {
            float xv = xs[m * DIN + i];
            ab += xv * b2[i * 32 + o];
            ar += xv * root[i * 32 + o];
        }
        size_t p = (size_t)(n0 + m) * 32 + o;
        xb2[p] = ab;
        agg[p] = ar;
    }
    __syncthreads();                           // LDS reuse across unit loop
}

// edge node: one wave handles node n (round-6 k_edge body)
__device__ __forceinline__ void edge_node(int n, int col, int quad,
                                          const float* wa, const float* wb, const float* bb,
                                          const int* __restrict__ off,
                                          const int* __restrict__ qmap,
                                          const float* __restrict__ ea_s,
                                          const unsigned short* __restrict__ Gb,
                                          const float* __restrict__ xb2,
                                          float* __restrict__ msgd) {
    const bf16x8 b_lo = *(const bf16x8*)(Gb + (size_t)n * 1024 + col * 32 + quad * 8);
    const bf16x8 b_hi = *(const bf16x8*)(Gb + (size_t)n * 1024 + (col + 16) * 32 + quad * 8);
    float xb_lo = xb2[(size_t)n * 32 + col];
    float xb_hi = xb2[(size_t)n * 32 + 16 + col];

    int jb = off[n], je = off[n + 1];
    for (int e0 = jb; e0 < je; e0 += 16) {
        int eA = e0 + col;
        bf16x8 afrag = {0, 0, 0, 0, 0, 0, 0, 0};
        if (eA < je) {
            float2 a = *(const float2*)(ea_s + 2 * (size_t)eA);
            union { unsigned int u[4]; bf16x8 v; } cv;
#pragma unroll
            for (int j = 0; j < 4; ++j) {
                float v0 = fmaxf(a.x * wa[2 * j]     + a.y * wb[2 * j]     + bb[2 * j],     0.f);
                float v1 = fmaxf(a.x * wa[2 * j + 1] + a.y * wb[2 * j + 1] + bb[2 * j + 1], 0.f);
                cv.u[j] = (unsigned int)f2b(v0) | ((unsigned int)f2b(v1) << 16);
            }
            afrag = cv.v;
        }
        f32x4 acc_lo = {xb_lo, xb_lo, xb_lo, xb_lo};
        f32x4 acc_hi = {xb_hi, xb_hi, xb_hi, xb_hi};
        acc_lo = __builtin_amdgcn_mfma_f32_16x16x32_bf16(afrag, b_lo, acc_lo, 0, 0, 0);
        acc_hi = __builtin_amdgcn_mfma_f32_16x16x32_bf16(afrag, b_hi, acc_hi, 0, 0, 0);
#pragma unroll
        for (int r = 0; r < 4; ++r) {
            int er = e0 + quad * 4 + r;
            if (er < je) {
                int q = qmap[er];
                msgd[(size_t)q * 32 + col] = acc_lo[r];
                msgd[(size_t)q * 32 + 16 + col] = acc_hi[r];
            }
        }
    }
}

// edge phase: loop nodes with hoisted per-lane W1 slice
__device__ __forceinline__ void edge_phase(const int* __restrict__ off,
                                           const int* __restrict__ qmap,
                                           const float* __restrict__ ea_s,
                                           const float* __restrict__ w1,
                                           const float* __restrict__ b1,
                                           const unsigned short* __restrict__ Gb,
                                           const float* __restrict__ xb2,
                                           float* __restrict__ msgd) {
    const int t = threadIdx.x;
    int lane = t & 63, wave = t >> 6;
    int col = lane & 15, quad = lane >> 4;
    float wa[8], wb[8], bb[8];
#pragma unroll
    for (int j = 0; j < 8; ++j) {
        int o = quad * 8 + j;
        wa[j] = w1[o];
        wb[j] = w1[32 + o];
        bb[j] = b1[o];
    }
    for (int u = blockIdx.x; u < 2500; u += NBLK)
        edge_node(u * 4 + wave, col, quad, wa, wb, bb, off, qmap, ea_s, Gb, xb2, msgd);
}

// final unit: 8 nodes starting at n0 (round-6 k_final body)
__device__ __forceinline__ void final_unit(int n0,
                                           const float* __restrict__ agg,
                                           const int* __restrict__ dst_off,
                                           const float* __restrict__ msgd,
                                           const float* __restrict__ fcw,
                                           const float* __restrict__ fcb,
                                           float* __restrict__ out,
                                           char* smem) {
    f64x4* part = (f64x4*)smem;
    float* xs = (float*)(smem + 8192);
    int t = threadIdx.x;
    {
        int m = t >> 5, s = t & 31;      // 8 nodes x (8 groups x 4 quarters)
        int g = s >> 2, quar = s & 3;
        int n = n0 + m;
        int jb = dst_off[n], je = dst_off[n + 1];
        f64x4 a0 = {0.0, 0.0, 0.0, 0.0}, a1 = {0.0, 0.0, 0.0, 0.0};
        int j = jb + quar;
        for (; j + 4 < je; j += 8) {
            f32x4 m0 = *(const f32x4*)(msgd + (size_t)j * 32 + g * 4);
            f32x4 m1 = *(const f32x4*)(msgd + (size_t)(j + 4) * 32 + g * 4);
            a0 += __builtin_convertvector(m0, f64x4);
            a1 += __builtin_convertvector(m1, f64x4);
        }
        if (j < je) {
            f32x4 m0 = *(const f32x4*)(msgd + (size_t)j * 32 + g * 4);
            a0 += __builtin_convertvector(m0, f64x4);
        }
        part[t] = a0 + a1;
    }
    __syncthreads();
    if (t < 64) {
        int m = t >> 3, g = t & 7;
        f64x4 v = part[m * 32 + g * 4] + part[m * 32 + g * 4 + 1] +
                  part[m * 32 + g * 4 + 2] + part[m * 32 + g * 4 + 3];
        int n = n0 + m;
        const f32x4 ag = *(const f32x4*)(agg + (size_t)n * 32 + g * 4);
        v += __builtin_convertvector(ag, f64x4);
#pragma unroll
        for (int c = 0; c < 4; ++c) {
            float f = (float)v[c];
            xs[m * 32 + g * 4 + c] = f > 0.f ? f : 0.f;
        }
    }
    __syncthreads();
    if (t < 8) {
        int nn = n0 + t;
        float l0 = fcb[0], l1 = fcb[1], l2 = fcb[2], l3 = fcb[3];
#pragma unroll
        for (int oo = 0; oo < 32; ++oo) {
            float xv = xs[t * 32 + oo];
            l0 += xv * fcw[oo * 4 + 0];
            l1 += xv * fcw[oo * 4 + 1];
            l2 += xv * fcw[oo * 4 + 2];
            l3 += xv * fcw[oo * 4 + 3];
        }
        float mx = fmaxf(fmaxf(l0, l1), fmaxf(l2, l3));
        float s = expf(l0 - mx) + expf(l1 - mx) + expf(l2 - mx) + expf(l3 - mx);
        float lse = mx + logf(s);
        out[(size_t)nn * 4 + 0] = l0 - lse;
        out[(size_t)nn * 4 + 1] = l1 - lse;
        out[(size_t)nn * 4 + 2] = l2 - lse;
        out[(size_t)nn * 4 + 3] = l3 - lse;
    }
    __syncthreads();                           // LDS reuse across unit loop
}

// ---------------- the mega kernel: whole pipeline, 8 grid barriers ----------------
__global__ __launch_bounds__(256, 4) void k_mega(
        const int* __restrict__ ei, const float* __restrict__ ea, const float* __restrict__ x0,
        const float* __restrict__ w1a, const float* __restrict__ b1a,
        const float* __restrict__ w1b, const float* __restrict__ b1b,
        const float* __restrict__ w1c, const float* __restrict__ b1c,
        const float* __restrict__ w2t0, const float* __restrict__ w2t1, const float* __restrict__ w2t2,
        const float* __restrict__ b2a, const float* __restrict__ b2b, const float* __restrict__ b2c,
        const float* __restrict__ rta, const float* __restrict__ rtb, const float* __restrict__ rtc,
        const float* __restrict__ bsa, const float* __restrict__ bsb, const float* __restrict__ bsc,
        const float* __restrict__ fcw, const float* __restrict__ fcb,
        int* cnt, int* cntd, int* cursor, int* cursord, int* off, int* dst_off, int* qmap,
        float* ea_s, float* xb2, float* aggA, float* aggB, float* msgd,
        unsigned short* Gb, int* bar, float* out) {
    __shared__ __align__(32) char smem[9216];
    const int t = threadIdx.x;
    const int bid = blockIdx.x;
    int* flags = bar;
    int* genp = bar + 1024;

    // ---- P1: dual histogram ----
    for (int u = bid; u < 625; u += NBLK) {
        int e = u * 256 + t;
        atomicAdd(&cnt[ei[e]], 1);
        atomicAdd(&cntd[ei[N_EDGES + e]], 1);
    }
    grid_sync(flags, genp, 1);

    // ---- P2: scans (blocks 0,1) ----
    if (bid == 0) scan_body(cnt, off, cursor, smem);
    else if (bid == 1) scan_body(cntd, dst_off, cursord, smem);
    grid_sync(flags, genp, 2);

    // ---- P3: scatter (625 units) in parallel with G0 (1250 units) ----
    for (int u = bid; u < 1875; u += NBLK) {
        if (u < 1250) {
            G_unit<4, true>(u * 8, x0, dst_off, msgd, w2t0, b2a, rta, bsa, Gb, xb2, aggA, smem);
        } else {
            int e = (u - 1250) * 256 + t;
            float a0 = ea[2 * e], a1 = ea[2 * e + 1];
            int src = ei[e], dst = ei[N_EDGES + e];
            int pos = atomicAdd(&cursor[src], 1);
            int q = atomicAdd(&cursord[dst], 1);
            qmap[pos] = q;
            *(float2*)(ea_s + 2 * (size_t)pos) = make_float2(a0, a1);
        }
    }
    grid_sync(flags, genp, 3);

    // ---- P4: edge0 ----
    edge_phase(off, qmap, ea_s, w1a, b1a, Gb, xb2, msgd);
    grid_sync(flags, genp, 4);

    // ---- P5: G1 ----
    for (int u = bid; u < 1250; u += NBLK)
        G_unit<32, false>(u * 8, aggA, dst_off, msgd, w2t1, b2b, rtb, bsb, Gb, xb2, aggB, smem);
    grid_sync(flags, genp, 5);

    // ---- P6: edge1 ----
    edge_phase(off, qmap, ea_s, w1b, b1b, Gb, xb2, msgd);
    grid_sync(flags, genp, 6);

    // ---- P7: G2 ----
    for (int u = bid; u < 1250; u += NBLK)
        G_unit<32, false>(u * 8, aggB, dst_off, msgd, w2t2, b2c, rtc, bsc, Gb, xb2, aggA, smem);
    grid_sync(flags, genp, 7);

    // ---- P8: edge2 ----
    edge_phase(off, qmap, ea_s, w1c, b1c, Gb, xb2, msgd);
    grid_sync(flags, genp, 8);

    // ---- P9: head ----
    for (int u = bid; u < 1250; u += NBLK)
        final_unit(u * 8, aggA, dst_off, msgd, fcw, fcb, out, smem);
}

extern "C" void kernel_launch(void* const* d_in, const int* in_sizes, int n_in,
                              void* d_out, int out_size, void* d_ws, size_t ws_size,
                              hipStream_t stream) {
    const float* x0 = (const float*)d_in[0];
    const int*   ei = (const int*)d_in[1];
    const float* ea = (const float*)d_in[2];
    const float *W1[3], *B1[3], *W2[3], *B2[3], *RT[3], *BS[3];
    for (int l = 0; l < 3; ++l) {
        W1[l] = (const float*)d_in[3 + 6 * l];
        B1[l] = (const float*)d_in[4 + 6 * l];
        W2[l] = (const float*)d_in[5 + 6 * l];
        B2[l] = (const float*)d_in[6 + 6 * l];
        RT[l] = (const float*)d_in[7 + 6 * l];
        BS[l] = (const float*)d_in[8 + 6 * l];
    }
    const float* fcw = (const float*)d_in[21];
    const float* fcb = (const float*)d_in[22];
    float* out = (float*)d_out;

    // ---- workspace layout (all segment starts 16B-aligned) ----
    int*   cnt     = (int*)d_ws;                      // 10240
    int*   cntd    = cnt + 10240;                     // 10240
    int*   bar     = cntd + 10240;                    // 1280 (flags[512] @ bar, gen @ bar+1024)
    int*   cursor  = bar + 1280;                      // 10240
    int*   cursord = cursor + 10240;                  // 10240
    int*   off     = cursord + 10240;                 // 10240 (10001 used)
    int*   dst_off = off + 10240;                     // 10240 (10001 used)
    int*   qmap    = dst_off + 10240;                 // 160000
    float* w2t0    = (float*)(qmap + 160000);         // 4096
    float* w2t1    = w2t0 + 4096;                     // 32768
    float* w2t2    = w2t1 + 32768;                    // 32768
    float* xb2     = w2t2 + 32768;                    // 320000
    float* aggA    = xb2 + 320000;                    // 320000
    float* aggB    = aggA + 320000;                   // 320000
    float* msgd    = aggB + 320000;                   // 5,120,000 f32 (E x 32, dst-sorted)
    float* ea_s    = msgd + 5120000;                  // 320,000 f32 (E x 2, src-sorted)
    unsigned short* Gb = (unsigned short*)(ea_s + 320000);   // 10,240,000 bf16

    // ---- 2 launches total ----
    k_pre<<<357, 256, 0, stream>>>(W2[0], W2[1], W2[2], w2t0, w2t1, w2t2, cnt);
    k_mega<<<NBLK, 256, 0, stream>>>(ei, ea, x0,
                                     W1[0], B1[0], W1[1], B1[1], W1[2], B1[2],
                                     w2t0, w2t1, w2t2,
                                     B2[0], B2[1], B2[2],
                                     RT[0], RT[1], RT[2],
                                     BS[0], BS[1], BS[2],
                                     fcw, fcb,
                                     cnt, cntd, cursor, cursord, off, dst_off, qmap,
                                     ea_s, xb2, aggA, aggB, msgd,
                                     Gb, bar, out);
}

// Round 8
// 252.710 us; speedup vs baseline: 3.6019x; 3.6019x over previous
//
#include <hip/hip_runtime.h>
#include <hip/hip_bf16.h>
#include <math.h>

#define N_NODES 10000
#define N_EDGES 160000

typedef __attribute__((ext_vector_type(8))) short bf16x8;
typedef __attribute__((ext_vector_type(4))) float f32x4;
typedef __attribute__((ext_vector_type(4))) double f64x4;

static __device__ inline unsigned short f2b(float v) {
    __hip_bfloat16 b = __float2bfloat16(v);
    return *reinterpret_cast<unsigned short*>(&b);
}
static __device__ inline float b2f(unsigned short u) {
    union { unsigned int i; float f; } c;
    c.i = ((unsigned int)u) << 16;
    return c.f;
}

// ---------- zero cnt+cntd (contiguous 20480 ints) + transpose all three w2 ----------
// w2t[i*1024 + o*32 + k] = w2[k*(din*32) + i*32 + o]
__global__ __launch_bounds__(256) void k_tw2z(const float* __restrict__ s0,
                                              const float* __restrict__ s1,
                                              const float* __restrict__ s2,
                                              float* __restrict__ t0,
                                              float* __restrict__ t1,
                                              float* __restrict__ t2,
                                              int* __restrict__ cntz) {
    int tid = blockIdx.x * 256 + threadIdx.x;
    if (tid < 20480) { cntz[tid] = 0; return; }
    int d = tid - 20480;
    if (d < 4096) {                            // layer 0, din=4
        int i = d >> 10, j = d & 1023, o = j >> 5, k = j & 31;
        t0[d] = s0[k * 128 + i * 32 + o];
    } else if (d < 4096 + 32768) {
        int q = d - 4096;
        int i = q >> 10, j = q & 1023, o = j >> 5, k = j & 31;
        t1[q] = s1[k * 1024 + i * 32 + o];
    } else if (d < 4096 + 65536) {
        int q = d - 4096 - 32768;
        int i = q >> 10, j = q & 1023, o = j >> 5, k = j & 31;
        t2[q] = s2[k * 1024 + i * 32 + o];
    }
}

// ---------- counting sort hists: by src AND by dst ----------
__global__ __launch_bounds__(256) void k_hist2(const int* __restrict__ ei,
                                               int* __restrict__ cnt,
                                               int* __restrict__ cntd) {
    int e = blockIdx.x * 256 + threadIdx.x;
    if (e < N_EDGES) {
        atomicAdd(&cnt[ei[e]], 1);
        atomicAdd(&cntd[ei[N_EDGES + e]], 1);
    }
}

// 2 blocks: block 0 scans src-cnt -> off/cursor, block 1 scans dst-cnt -> dst_off/cursord
__global__ __launch_bounds__(256) void k_scan2(const int* __restrict__ cnt,
                                               const int* __restrict__ cntd,
                                               int* __restrict__ off,
                                               int* __restrict__ dst_off,
                                               int* __restrict__ cursor,
                                               int* __restrict__ cursord) {
    const int* c; int* o; int* cu;
    if (blockIdx.x == 0) { c = cnt;  o = off;     cu = cursor;  }
    else                 { c = cntd; o = dst_off; cu = cursord; }
    __shared__ int part[256];
    int t = threadIdx.x;
    int base = t * 40;
    int s = 0;
    for (int i = 0; i < 40; ++i) {
        int idx = base + i;
        if (idx < N_NODES) s += c[idx];
    }
    part[t] = s;
    __syncthreads();
    for (int d = 1; d < 256; d <<= 1) {
        int v = (t >= d) ? part[t - d] : 0;
        __syncthreads();
        part[t] += v;
        __syncthreads();
    }
    int run = part[t] - s;
    for (int i = 0; i < 40; ++i) {
        int idx = base + i;
        if (idx < N_NODES) {
            o[idx] = run;
            cu[idx] = run;
            run += c[idx];
        }
    }
    if (t == 255) o[N_NODES] = run;
}

// ---------- scatter edges into src-sorted order: record dst-sorted slot (qmap)
//            and src-sorted edge_attr (ea_s). ----------
__global__ __launch_bounds__(256) void k_scatter(const int* __restrict__ ei,
                                                 const float* __restrict__ ea,
                                                 int* __restrict__ cursor,
                                                 int* __restrict__ cursord,
                                                 int* __restrict__ qmap,
                                                 float* __restrict__ ea_s) {
    int e = blockIdx.x * 256 + threadIdx.x;
    if (e >= N_EDGES) return;
    float a0 = ea[2 * e], a1 = ea[2 * e + 1];
    int src = ei[e], dst = ei[N_EDGES + e];
    int pos = atomicAdd(&cursor[src], 1);    // slot in src-sorted order (k_edge iteration order)
    int q   = atomicAdd(&cursord[dst], 1);   // slot in dst-sorted order (msg landing)
    qmap[pos] = q;
    *(float2*)(ea_s + 2 * (size_t)pos) = make_float2(a0, a1);
}

// ---------- G[n, o*32+k] (bf16) = sum_i x[n,i]*w2t[i, o*32+k]; also xb2, agg-init (fp32) ----------
// 8 nodes/block. Non-FIRST gather reads bf16 msgd rows (64B), accumulates in fp64
// -> exact, order-independent under the qmap permutation (call-stable output).
// msgd row layout: element j = 2*col + half  <->  channel col + 16*half.
template <int DIN, bool FIRST>
__global__ __launch_bounds__(256) void k_G(const float* __restrict__ xin,   // FIRST: x0, else aggPrev
                                           const int* __restrict__ dst_off,
                                           const unsigned short* __restrict__ msgd,
                                           const float* __restrict__ w2t,  // [DIN,1024]
                                           const float* __restrict__ b2,   // [DIN*32]
                                           const float* __restrict__ root, // [DIN,32]
                                           const float* __restrict__ bias, // [32]
                                           unsigned short* __restrict__ Gb,
                                           float* __restrict__ xb2,
                                           float* __restrict__ agg) {
    const int t = threadIdx.x;
    const int n0 = blockIdx.x * 8;

    __shared__ float xs[8 * DIN];
    if constexpr (FIRST) {
        for (int idx = t; idx < 8 * DIN; idx += 256) {
            int m = idx / DIN, i = idx - m * DIN;
            xs[idx] = xin[(size_t)(n0 + m) * DIN + i];
        }
        __syncthreads();
    } else {
        // DIN == 32: 32 threads/node = 8 element-groups (4 row-elements = 8B) x 4 slot-quarters.
        __shared__ f64x4 part[256];
        {
            int m = t >> 5, s = t & 31;
            int g = s >> 2, quar = s & 3;
            int n = n0 + m;
            int jb = dst_off[n], je = dst_off[n + 1];
            f64x4 a0 = {0.0, 0.0, 0.0, 0.0}, a1 = {0.0, 0.0, 0.0, 0.0};
            int j = jb + quar;
            for (; j + 4 < je; j += 8) {
                ushort4 u0 = *(const ushort4*)(msgd + (size_t)j * 32 + g * 4);
                ushort4 u1 = *(const ushort4*)(msgd + (size_t)(j + 4) * 32 + g * 4);
                a0[0] += (double)b2f(u0.x); a0[1] += (double)b2f(u0.y);
                a0[2] += (double)b2f(u0.z); a0[3] += (double)b2f(u0.w);
                a1[0] += (double)b2f(u1.x); a1[1] += (double)b2f(u1.y);
                a1[2] += (double)b2f(u1.z); a1[3] += (double)b2f(u1.w);
            }
            if (j < je) {
                ushort4 u0 = *(const ushort4*)(msgd + (size_t)j * 32 + g * 4);
                a0[0] += (double)b2f(u0.x); a0[1] += (double)b2f(u0.y);
                a0[2] += (double)b2f(u0.z); a0[3] += (double)b2f(u0.w);
            }
            part[t] = a0 + a1;
        }
        __syncthreads();
        if (t < 64) {
            int m = t >> 3, g = t & 7;
            f64x4 v = part[m * 32 + g * 4] + part[m * 32 + g * 4 + 1] +
                      part[m * 32 + g * 4 + 2] + part[m * 32 + g * 4 + 3];
            int n = n0 + m;
            // element i of v -> channel: i=0: 2g, i=1: 2g+16, i=2: 2g+1, i=3: 2g+17
            float2 xiA = *(const float2*)(xin + (size_t)n * 32 + 2 * g);
            float2 xiB = *(const float2*)(xin + (size_t)n * 32 + 16 + 2 * g);
            float r0 = (float)(v[0] + (double)xiA.x);  // c = 2g
            float r2 = (float)(v[2] + (double)xiA.y);  // c = 2g+1
            float r1 = (float)(v[1] + (double)xiB.x);  // c = 2g+16
            float r3 = (float)(v[3] + (double)xiB.y);  // c = 2g+17
            xs[m * 32 + 2 * g]      = r0 > 0.f ? r0 : 0.f;
            xs[m * 32 + 2 * g + 1]  = r2 > 0.f ? r2 : 0.f;
            xs[m * 32 + 2 * g + 16] = r1 > 0.f ? r1 : 0.f;
            xs[m * 32 + 2 * g + 17] = r3 > 0.f ? r3 : 0.f;
        }
        __syncthreads();
    }

    float acc[8][4];
#pragma unroll
    for (int m = 0; m < 8; ++m)
        acc[m][0] = acc[m][1] = acc[m][2] = acc[m][3] = 0.f;

#pragma unroll
    for (int i = 0; i < DIN; ++i) {
        const float4 w = *(const float4*)(w2t + i * 1024 + t * 4);
#pragma unroll
        for (int m = 0; m < 8; ++m) {
            float xv = xs[m * DIN + i];
            acc[m][0] += xv * w.x;
            acc[m][1] += xv * w.y;
            acc[m][2] += xv * w.z;
            acc[m][3] += xv * w.w;
        }
    }
#pragma unroll
    for (int m = 0; m < 8; ++m) {
        unsigned int p0 = (unsigned int)f2b(acc[m][0]) | ((unsigned int)f2b(acc[m][1]) << 16);
        unsigned int p1 = (unsigned int)f2b(acc[m][2]) | ((unsigned int)f2b(acc[m][3]) << 16);
        *(uint2*)(Gb + (size_t)(n0 + m) * 1024 + t * 4) = make_uint2(p0, p1);
    }

    {
        int m = t >> 5, o = t & 31;              // 8*32 = 256 = blockDim
        float ab = 0.f, ar = bias[o];
#pragma unroll
        for (int i = 0; i < DIN; ++i) {
            float xv = xs[m * DIN + i];
            ab += xv * b2[i * 32 + o];
            ar += xv * root[i * 32 + o];
        }
        size_t p = (size_t)(n0 + m) * 32 + o;
        xb2[p] = ab;
        agg[p] = ar;
    }
}

// ---------- MFMA edge kernel: one wave per node ----------
// msg[E_tile(16) x 32] = H_tile(16x32) @ G_n^T, acc init = xb2 broadcast.
// h recomputed IN-REGISTER from src-sorted edge_attr.
// Messages stored bf16-PACKED: one 4B store per lane per row (lo|hi<<16).
__global__ __launch_bounds__(256) void k_edge(const int* __restrict__ off,
                                              const int* __restrict__ qmap,
                                              const float* __restrict__ ea_s, // [E,2] src-sorted
                                              const float* __restrict__ w1,   // [2,32]
                                              const float* __restrict__ b1,   // [32]
                                              const unsigned short* __restrict__ Gb,
                                              const float* __restrict__ xb2,
                                              unsigned short* __restrict__ msgd) {
    int t = threadIdx.x;
    int lane = t & 63;
    int n = blockIdx.x * 4 + (t >> 6);
    int col = lane & 15;     // C col = o (low half); A row m = edge-in-tile
    int quad = lane >> 4;    // k-block selector

    // per-lane W1 slice for the 8 h-columns this lane feeds into the A-fragment
    float wa[8], wb[8], bb[8];
#pragma unroll
    for (int j = 0; j < 8; ++j) {
        int o = quad * 8 + j;
        wa[j] = w1[o];
        wb[j] = w1[32 + o];
        bb[j] = b1[o];
    }

    // B frags: B[k=quad*8+j][o=col] = G_n[o*32 + k]
    const bf16x8 b_lo = *(const bf16x8*)(Gb + (size_t)n * 1024 + col * 32 + quad * 8);
    const bf16x8 b_hi = *(const bf16x8*)(Gb + (size_t)n * 1024 + (col + 16) * 32 + quad * 8);
    float xb_lo = xb2[(size_t)n * 32 + col];
    float xb_hi = xb2[(size_t)n * 32 + 16 + col];

    int jb = off[n], je = off[n + 1];
    for (int e0 = jb; e0 < je; e0 += 16) {
        int eA = e0 + col;
        bf16x8 afrag = {0, 0, 0, 0, 0, 0, 0, 0};
        if (eA < je) {
            float2 a = *(const float2*)(ea_s + 2 * (size_t)eA);
            union { unsigned int u[4]; bf16x8 v; } cv;
#pragma unroll
            for (int j = 0; j < 4; ++j) {
                float v0 = fmaxf(a.x * wa[2 * j]     + a.y * wb[2 * j]     + bb[2 * j],     0.f);
                float v1 = fmaxf(a.x * wa[2 * j + 1] + a.y * wb[2 * j + 1] + bb[2 * j + 1], 0.f);
                cv.u[j] = (unsigned int)f2b(v0) | ((unsigned int)f2b(v1) << 16);
            }
            afrag = cv.v;
        }
        f32x4 acc_lo = {xb_lo, xb_lo, xb_lo, xb_lo};
        f32x4 acc_hi = {xb_hi, xb_hi, xb_hi, xb_hi};
        acc_lo = __builtin_amdgcn_mfma_f32_16x16x32_bf16(afrag, b_lo, acc_lo, 0, 0, 0);
        acc_hi = __builtin_amdgcn_mfma_f32_16x16x32_bf16(afrag, b_hi, acc_hi, 0, 0, 0);
#pragma unroll
        for (int r = 0; r < 4; ++r) {
            int er = e0 + quad * 4 + r;       // C row = edge-in-tile
            if (er < je) {
                int q = qmap[er];
                unsigned int pk = (unsigned int)f2b(acc_lo[r]) |
                                  ((unsigned int)f2b(acc_hi[r]) << 16);
                *(unsigned int*)(msgd + (size_t)q * 32 + col * 2) = pk;
            }
        }
    }
}

// ---------- head: gather last layer's bf16 messages (fp64) + relu + fc + log_softmax ----------
__global__ __launch_bounds__(256) void k_final(const float* __restrict__ agg,
                                               const int* __restrict__ dst_off,
                                               const unsigned short* __restrict__ msgd,
                                               const float* __restrict__ fcw,
                                               const float* __restrict__ fcb,
                                               float* __restrict__ out) {
    __shared__ f64x4 part[256];
    __shared__ float xs[8 * 32];
    int t = threadIdx.x;
    {
        int m = t >> 5, s = t & 31;      // 8 nodes x (8 element-groups x 4 slot-quarters)
        int g = s >> 2, quar = s & 3;
        int n = blockIdx.x * 8 + m;
        int jb = dst_off[n], je = dst_off[n + 1];
        f64x4 a0 = {0.0, 0.0, 0.0, 0.0}, a1 = {0.0, 0.0, 0.0, 0.0};
        int j = jb + quar;
        for (; j + 4 < je; j += 8) {
            ushort4 u0 = *(const ushort4*)(msgd + (size_t)j * 32 + g * 4);
            ushort4 u1 = *(const ushort4*)(msgd + (size_t)(j + 4) * 32 + g * 4);
            a0[0] += (double)b2f(u0.x); a0[1] += (double)b2f(u0.y);
            a0[2] += (double)b2f(u0.z); a0[3] += (double)b2f(u0.w);
            a1[0] += (double)b2f(u1.x); a1[1] += (double)b2f(u1.y);
            a1[2] += (double)b2f(u1.z); a1[3] += (double)b2f(u1.w);
        }
        if (j < je) {
            ushort4 u0 = *(const ushort4*)(msgd + (size_t)j * 32 + g * 4);
            a0[0] += (double)b2f(u0.x); a0[1] += (double)b2f(u0.y);
            a0[2] += (double)b2f(u0.z); a0[3] += (double)b2f(u0.w);
        }
        part[t] = a0 + a1;
    }
    __syncthreads();
    if (t < 64) {
        int m = t >> 3, g = t & 7;
        f64x4 v = part[m * 32 + g * 4] + part[m * 32 + g * 4 + 1] +
                  part[m * 32 + g * 4 + 2] + part[m * 32 + g * 4 + 3];
        int n = blockIdx.x * 8 + m;
        float2 agA = *(const float2*)(agg + (size_t)n * 32 + 2 * g);
        float2 agB = *(const float2*)(agg + (size_t)n * 32 + 16 + 2 * g);
        float r0 = (float)(v[0] + (double)agA.x);  // c = 2g
        float r2 = (float)(v[2] + (double)agA.y);  // c = 2g+1
        float r1 = (float)(v[1] + (double)agB.x);  // c = 2g+16
        float r3 = (float)(v[3] + (double)agB.y);  // c = 2g+17
        xs[m * 32 + 2 * g]      = r0 > 0.f ? r0 : 0.f;
        xs[m * 32 + 2 * g + 1]  = r2 > 0.f ? r2 : 0.f;
        xs[m * 32 + 2 * g + 16] = r1 > 0.f ? r1 : 0.f;
        xs[m * 32 + 2 * g + 17] = r3 > 0.f ? r3 : 0.f;
    }
    __syncthreads();
    if (t < 8) {
        int nn = blockIdx.x * 8 + t;
        float l0 = fcb[0], l1 = fcb[1], l2 = fcb[2], l3 = fcb[3];
#pragma unroll
        for (int oo = 0; oo < 32; ++oo) {
            float xv = xs[t * 32 + oo];
            l0 += xv * fcw[oo * 4 + 0];
            l1 += xv * fcw[oo * 4 + 1];
            l2 += xv * fcw[oo * 4 + 2];
            l3 += xv * fcw[oo * 4 + 3];
        }
        float mx = fmaxf(fmaxf(l0, l1), fmaxf(l2, l3));
        float s = expf(l0 - mx) + expf(l1 - mx) + expf(l2 - mx) + expf(l3 - mx);
        float lse = mx + logf(s);
        out[(size_t)nn * 4 + 0] = l0 - lse;
        out[(size_t)nn * 4 + 1] = l1 - lse;
        out[(size_t)nn * 4 + 2] = l2 - lse;
        out[(size_t)nn * 4 + 3] = l3 - lse;
    }
}

extern "C" void kernel_launch(void* const* d_in, const int* in_sizes, int n_in,
                              void* d_out, int out_size, void* d_ws, size_t ws_size,
                              hipStream_t stream) {
    const float* x0 = (const float*)d_in[0];
    const int*   ei = (const int*)d_in[1];
    const float* ea = (const float*)d_in[2];
    const float *W1[3], *B1[3], *W2[3], *B2[3], *RT[3], *BS[3];
    for (int l = 0; l < 3; ++l) {
        W1[l] = (const float*)d_in[3 + 6 * l];
        B1[l] = (const float*)d_in[4 + 6 * l];
        W2[l] = (const float*)d_in[5 + 6 * l];
        B2[l] = (const float*)d_in[6 + 6 * l];
        RT[l] = (const float*)d_in[7 + 6 * l];
        BS[l] = (const float*)d_in[8 + 6 * l];
    }
    const float* fcw = (const float*)d_in[21];
    const float* fcb = (const float*)d_in[22];
    float* out = (float*)d_out;

    // ---- workspace layout (all segment starts 16B-aligned) ----
    int*   cnt     = (int*)d_ws;                      // 10240
    int*   cntd    = cnt + 10240;                     // 10240 (contiguous with cnt for zeroing)
    int*   cursor  = cntd + 10240;                    // 10240
    int*   cursord = cursor + 10240;                  // 10240
    int*   off     = cursord + 10240;                 // 10240 (10001 used)
    int*   dst_off = off + 10240;                     // 10240 (10001 used)
    int*   qmap    = dst_off + 10240;                 // 160000
    float* w2t0    = (float*)(qmap + 160000);         // 4096
    float* w2t1    = w2t0 + 4096;                     // 32768
    float* w2t2    = w2t1 + 32768;                    // 32768
    float* xb2     = w2t2 + 32768;                    // 320000
    float* aggA    = xb2 + 320000;                    // 320000
    float* aggB    = aggA + 320000;                   // 320000
    unsigned short* msgd = (unsigned short*)(aggB + 320000); // 5,120,000 bf16 (E x 32, dst-sorted)
    float* ea_s    = (float*)(msgd + 5120000);        // 320,000 f32 (E x 2, src-sorted)
    unsigned short* Gb = (unsigned short*)(ea_s + 320000);   // 10,240,000 bf16

    const int gE256 = (N_EDGES + 255) / 256;   // 625
    const int gG    = N_NODES / 8;             // 1250
    const int gEdge = N_NODES / 4;             // 2500 (1 wave per node, 4 waves/block)

    // ---- once-per-call preprocessing ----
    k_tw2z<<<352, 256, 0, stream>>>(W2[0], W2[1], W2[2], w2t0, w2t1, w2t2, cnt);
    k_hist2<<<gE256, 256, 0, stream>>>(ei, cnt, cntd);
    k_scan2<<<2, 256, 0, stream>>>(cnt, cntd, off, dst_off, cursor, cursord);
    k_scatter<<<gE256, 256, 0, stream>>>(ei, ea, cursor, cursord, qmap, ea_s);

    // ---- layer 0 (din=4) ----
    k_G<4, true><<<gG, 256, 0, stream>>>(x0, dst_off, msgd, w2t0, B2[0], RT[0], BS[0], Gb, xb2, aggA);
    k_edge<<<gEdge, 256, 0, stream>>>(off, qmap, ea_s, W1[0], B1[0], Gb, xb2, msgd);

    // ---- layer 1 (din=32): k_G gathers layer-0 messages on the fly ----
    k_G<32, false><<<gG, 256, 0, stream>>>(aggA, dst_off, msgd, w2t1, B2[1], RT[1], BS[1], Gb, xb2, aggB);
    k_edge<<<gEdge, 256, 0, stream>>>(off, qmap, ea_s, W1[1], B1[1], Gb, xb2, msgd);

    // ---- layer 2 (din=32) ----
    k_G<32, false><<<gG, 256, 0, stream>>>(aggB, dst_off, msgd, w2t2, B2[2], RT[2], BS[2], Gb, xb2, aggA);
    k_edge<<<gEdge, 256, 0, stream>>>(off, qmap, ea_s, W1[2], B1[2], Gb, xb2, msgd);

    // ---- head ----
    k_final<<<(N_NODES + 7) / 8, 256, 0, stream>>>(aggA, dst_off, msgd, fcw, fcb, out);
}

// Round 9
// 244.513 us; speedup vs baseline: 3.7226x; 1.0335x over previous
//
#include <hip/hip_runtime.h>
#include <hip/hip_bf16.h>
#include <math.h>

#define N_NODES 10000
#define N_EDGES 160000

typedef __attribute__((ext_vector_type(8))) short bf16x8;
typedef __attribute__((ext_vector_type(4))) float f32x4;
typedef __attribute__((ext_vector_type(4))) double f64x4;

static __device__ inline unsigned short f2b(float v) {
    __hip_bfloat16 b = __float2bfloat16(v);
    return *reinterpret_cast<unsigned short*>(&b);
}
static __device__ inline float b2f(unsigned short u) {
    union { unsigned int i; float f; } c;
    c.i = ((unsigned int)u) << 16;
    return c.f;
}

// ---------- zero cnt+cntd (contiguous 20480 ints) + transpose all three w2 ----------
// w2t[i*1024 + o*32 + k] = w2[k*(din*32) + i*32 + o]
__global__ __launch_bounds__(256) void k_tw2z(const float* __restrict__ s0,
                                              const float* __restrict__ s1,
                                              const float* __restrict__ s2,
                                              float* __restrict__ t0,
                                              float* __restrict__ t1,
                                              float* __restrict__ t2,
                                              int* __restrict__ cntz) {
    int tid = blockIdx.x * 256 + threadIdx.x;
    if (tid < 20480) { cntz[tid] = 0; return; }
    int d = tid - 20480;
    if (d < 4096) {                            // layer 0, din=4
        int i = d >> 10, j = d & 1023, o = j >> 5, k = j & 31;
        t0[d] = s0[k * 128 + i * 32 + o];
    } else if (d < 4096 + 32768) {
        int q = d - 4096;
        int i = q >> 10, j = q & 1023, o = j >> 5, k = j & 31;
        t1[q] = s1[k * 1024 + i * 32 + o];
    } else if (d < 4096 + 65536) {
        int q = d - 4096 - 32768;
        int i = q >> 10, j = q & 1023, o = j >> 5, k = j & 31;
        t2[q] = s2[k * 1024 + i * 32 + o];
    }
}

// ---------- counting sort hists: by src AND by dst ----------
__global__ __launch_bounds__(256) void k_hist2(const int* __restrict__ ei,
                                               int* __restrict__ cnt,
                                               int* __restrict__ cntd) {
    int e = blockIdx.x * 256 + threadIdx.x;
    if (e < N_EDGES) {
        atomicAdd(&cnt[ei[e]], 1);
        atomicAdd(&cntd[ei[N_EDGES + e]], 1);
    }
}

// 2 blocks: block 0 scans src-cnt -> off/cursor, block 1 scans dst-cnt -> dst_off/cursord
__global__ __launch_bounds__(256) void k_scan2(const int* __restrict__ cnt,
                                               const int* __restrict__ cntd,
                                               int* __restrict__ off,
                                               int* __restrict__ dst_off,
                                               int* __restrict__ cursor,
                                               int* __restrict__ cursord) {
    const int* c; int* o; int* cu;
    if (blockIdx.x == 0) { c = cnt;  o = off;     cu = cursor;  }
    else                 { c = cntd; o = dst_off; cu = cursord; }
    __shared__ int part[256];
    int t = threadIdx.x;
    int base = t * 40;
    int s = 0;
    for (int i = 0; i < 40; ++i) {
        int idx = base + i;
        if (idx < N_NODES) s += c[idx];
    }
    part[t] = s;
    __syncthreads();
    for (int d = 1; d < 256; d <<= 1) {
        int v = (t >= d) ? part[t - d] : 0;
        __syncthreads();
        part[t] += v;
        __syncthreads();
    }
    int run = part[t] - s;
    for (int i = 0; i < 40; ++i) {
        int idx = base + i;
        if (idx < N_NODES) {
            o[idx] = run;
            cu[idx] = run;
            run += c[idx];
        }
    }
    if (t == 255) o[N_NODES] = run;
}

// ---------- scatter edges into src-sorted order: record dst-sorted slot (qmap)
//            and src-sorted edge_attr (ea_s). ----------
__global__ __launch_bounds__(256) void k_scatter(const int* __restrict__ ei,
                                                 const float* __restrict__ ea,
                                                 int* __restrict__ cursor,
                                                 int* __restrict__ cursord,
                                                 int* __restrict__ qmap,
                                                 float* __restrict__ ea_s) {
    int e = blockIdx.x * 256 + threadIdx.x;
    if (e >= N_EDGES) return;
    float a0 = ea[2 * e], a1 = ea[2 * e + 1];
    int src = ei[e], dst = ei[N_EDGES + e];
    int pos = atomicAdd(&cursor[src], 1);    // slot in src-sorted order (edge iteration order)
    int q   = atomicAdd(&cursord[dst], 1);   // slot in dst-sorted order (msg landing)
    qmap[pos] = q;
    *(float2*)(ea_s + 2 * (size_t)pos) = make_float2(a0, a1);
}

// ---------- FUSED per-layer kernel: round-8 k_G body + barrier + round-8 k_edge body ----------
// 8 nodes/block, grid 1250. G-phase writes Gb/xb2/agg to GLOBAL exactly as round 8;
// edge-phase reads the same Gb/xb2 rows (just written by THIS block -> L2-hot, ordered by
// the vmcnt(0)+barrier of __syncthreads). msgd double-buffered: gather reads msgd_in,
// edge writes msgd_out (disjoint) -> no intra-launch cross-block hazard.
template <int DIN, bool FIRST>
__global__ __launch_bounds__(256) void k_GE(const float* __restrict__ xin,   // FIRST: x0, else aggPrev
                                            const int* __restrict__ dst_off,
                                            const unsigned short* __restrict__ msgd_in,
                                            const float* __restrict__ w2t,  // [DIN,1024]
                                            const float* __restrict__ b2,   // [DIN*32]
                                            const float* __restrict__ root, // [DIN,32]
                                            const float* __restrict__ bias, // [32]
                                            const int* __restrict__ off,
                                            const int* __restrict__ qmap,
                                            const float* __restrict__ ea_s, // [E,2] src-sorted
                                            const float* __restrict__ w1,   // [2,32]
                                            const float* __restrict__ b1,   // [32]
                                            unsigned short* __restrict__ Gb,
                                            float* __restrict__ xb2,
                                            float* __restrict__ agg,
                                            unsigned short* __restrict__ msgd_out) {
    const int t = threadIdx.x;
    const int n0 = blockIdx.x * 8;

    __shared__ float xs[8 * DIN];
    if constexpr (FIRST) {
        for (int idx = t; idx < 8 * DIN; idx += 256) {
            int m = idx / DIN, i = idx - m * DIN;
            xs[idx] = xin[(size_t)(n0 + m) * DIN + i];
        }
        __syncthreads();
    } else {
        // DIN == 32: 32 threads/node = 8 element-groups (4 row-elements = 8B) x 4 slot-quarters.
        __shared__ f64x4 part[256];
        {
            int m = t >> 5, s = t & 31;
            int g = s >> 2, quar = s & 3;
            int n = n0 + m;
            int jb = dst_off[n], je = dst_off[n + 1];
            f64x4 a0 = {0.0, 0.0, 0.0, 0.0}, a1 = {0.0, 0.0, 0.0, 0.0};
            int j = jb + quar;
            for (; j + 4 < je; j += 8) {
                ushort4 u0 = *(const ushort4*)(msgd_in + (size_t)j * 32 + g * 4);
                ushort4 u1 = *(const ushort4*)(msgd_in + (size_t)(j + 4) * 32 + g * 4);
                a0[0] += (double)b2f(u0.x); a0[1] += (double)b2f(u0.y);
                a0[2] += (double)b2f(u0.z); a0[3] += (double)b2f(u0.w);
                a1[0] += (double)b2f(u1.x); a1[1] += (double)b2f(u1.y);
                a1[2] += (double)b2f(u1.z); a1[3] += (double)b2f(u1.w);
            }
            if (j < je) {
                ushort4 u0 = *(const ushort4*)(msgd_in + (size_t)j * 32 + g * 4);
                a0[0] += (double)b2f(u0.x); a0[1] += (double)b2f(u0.y);
                a0[2] += (double)b2f(u0.z); a0[3] += (double)b2f(u0.w);
            }
            part[t] = a0 + a1;
        }
        __syncthreads();
        if (t < 64) {
            int m = t >> 3, g = t & 7;
            f64x4 v = part[m * 32 + g * 4] + part[m * 32 + g * 4 + 1] +
                      part[m * 32 + g * 4 + 2] + part[m * 32 + g * 4 + 3];
            int n = n0 + m;
            // element i of v -> channel: i=0: 2g, i=1: 2g+16, i=2: 2g+1, i=3: 2g+17
            float2 xiA = *(const float2*)(xin + (size_t)n * 32 + 2 * g);
            float2 xiB = *(const float2*)(xin + (size_t)n * 32 + 16 + 2 * g);
            float r0 = (float)(v[0] + (double)xiA.x);  // c = 2g
            float r2 = (float)(v[2] + (double)xiA.y);  // c = 2g+1
            float r1 = (float)(v[1] + (double)xiB.x);  // c = 2g+16
            float r3 = (float)(v[3] + (double)xiB.y);  // c = 2g+17
            xs[m * 32 + 2 * g]      = r0 > 0.f ? r0 : 0.f;
            xs[m * 32 + 2 * g + 1]  = r2 > 0.f ? r2 : 0.f;
            xs[m * 32 + 2 * g + 16] = r1 > 0.f ? r1 : 0.f;
            xs[m * 32 + 2 * g + 17] = r3 > 0.f ? r3 : 0.f;
        }
        __syncthreads();
    }

    // ---- G GEMM (verbatim round-8) ----
    {
        float acc[8][4];
#pragma unroll
        for (int m = 0; m < 8; ++m)
            acc[m][0] = acc[m][1] = acc[m][2] = acc[m][3] = 0.f;

#pragma unroll
        for (int i = 0; i < DIN; ++i) {
            const float4 w = *(const float4*)(w2t + i * 1024 + t * 4);
#pragma unroll
            for (int m = 0; m < 8; ++m) {
                float xv = xs[m * DIN + i];
                acc[m][0] += xv * w.x;
                acc[m][1] += xv * w.y;
                acc[m][2] += xv * w.z;
                acc[m][3] += xv * w.w;
            }
        }
#pragma unroll
        for (int m = 0; m < 8; ++m) {
            unsigned int p0 = (unsigned int)f2b(acc[m][0]) | ((unsigned int)f2b(acc[m][1]) << 16);
            unsigned int p1 = (unsigned int)f2b(acc[m][2]) | ((unsigned int)f2b(acc[m][3]) << 16);
            *(uint2*)(Gb + (size_t)(n0 + m) * 1024 + t * 4) = make_uint2(p0, p1);
        }

        {
            int m = t >> 5, o = t & 31;              // 8*32 = 256 = blockDim
            float ab = 0.f, ar = bias[o];
#pragma unroll
            for (int i = 0; i < DIN; ++i) {
                float xv = xs[m * DIN + i];
                ab += xv * b2[i * 32 + o];
                ar += xv * root[i * 32 + o];
            }
            size_t p = (size_t)(n0 + m) * 32 + o;
            xb2[p] = ab;
            agg[p] = ar;
        }
    }

    // Gb/xb2 stores must be drained & visible block-wide before the edge phase reads them.
    __syncthreads();

    // ---- edge phase (verbatim round-8 k_edge): 4 waves x 2 nodes ----
    {
        int lane = t & 63, wave = t >> 6;
        int col = lane & 15;     // C col = o (low half); A row m = edge-in-tile
        int quad = lane >> 4;    // k-block selector

        float wa[8], wb[8], bb[8];
#pragma unroll
        for (int j = 0; j < 8; ++j) {
            int o = quad * 8 + j;
            wa[j] = w1[o];
            wb[j] = w1[32 + o];
            bb[j] = b1[o];
        }

        for (int nn = 0; nn < 2; ++nn) {
            int n = n0 + wave * 2 + nn;
            const bf16x8 b_lo = *(const bf16x8*)(Gb + (size_t)n * 1024 + col * 32 + quad * 8);
            const bf16x8 b_hi = *(const bf16x8*)(Gb + (size_t)n * 1024 + (col + 16) * 32 + quad * 8);
            float xb_lo = xb2[(size_t)n * 32 + col];
            float xb_hi = xb2[(size_t)n * 32 + 16 + col];

            int jb = off[n], je = off[n + 1];
            for (int e0 = jb; e0 < je; e0 += 16) {
                int eA = e0 + col;
                bf16x8 afrag = {0, 0, 0, 0, 0, 0, 0, 0};
                if (eA < je) {
                    float2 a = *(const float2*)(ea_s + 2 * (size_t)eA);
                    union { unsigned int u[4]; bf16x8 v; } cv;
#pragma unroll
                    for (int j = 0; j < 4; ++j) {
                        float v0 = fmaxf(a.x * wa[2 * j]     + a.y * wb[2 * j]     + bb[2 * j],     0.f);
                        float v1 = fmaxf(a.x * wa[2 * j + 1] + a.y * wb[2 * j + 1] + bb[2 * j + 1], 0.f);
                        cv.u[j] = (unsigned int)f2b(v0) | ((unsigned int)f2b(v1) << 16);
                    }
                    afrag = cv.v;
                }
                f32x4 acc_lo = {xb_lo, xb_lo, xb_lo, xb_lo};
                f32x4 acc_hi = {xb_hi, xb_hi, xb_hi, xb_hi};
                acc_lo = __builtin_amdgcn_mfma_f32_16x16x32_bf16(afrag, b_lo, acc_lo, 0, 0, 0);
                acc_hi = __builtin_amdgcn_mfma_f32_16x16x32_bf16(afrag, b_hi, acc_hi, 0, 0, 0);
#pragma unroll
                for (int r = 0; r < 4; ++r) {
                    int er = e0 + quad * 4 + r;       // C row = edge-in-tile
                    if (er < je) {
                        int q = qmap[er];
                        unsigned int pk = (unsigned int)f2b(acc_lo[r]) |
                                          ((unsigned int)f2b(acc_hi[r]) << 16);
                        *(unsigned int*)(msgd_out + (size_t)q * 32 + col * 2) = pk;
                    }
                }
            }
        }
    }
}

// ---------- head: gather last layer's bf16 messages (fp64) + relu + fc + log_softmax ----------
__global__ __launch_bounds__(256) void k_final(const float* __restrict__ agg,
                                               const int* __restrict__ dst_off,
                                               const unsigned short* __restrict__ msgd,
                                               const float* __restrict__ fcw,
                                               const float* __restrict__ fcb,
                                               float* __restrict__ out) {
    __shared__ f64x4 part[256];
    __shared__ float xs[8 * 32];
    int t = threadIdx.x;
    {
        int m = t >> 5, s = t & 31;      // 8 nodes x (8 element-groups x 4 slot-quarters)
        int g = s >> 2, quar = s & 3;
        int n = blockIdx.x * 8 + m;
        int jb = dst_off[n], je = dst_off[n + 1];
        f64x4 a0 = {0.0, 0.0, 0.0, 0.0}, a1 = {0.0, 0.0, 0.0, 0.0};
        int j = jb + quar;
        for (; j + 4 < je; j += 8) {
            ushort4 u0 = *(const ushort4*)(msgd + (size_t)j * 32 + g * 4);
            ushort4 u1 = *(const ushort4*)(msgd + (size_t)(j + 4) * 32 + g * 4);
            a0[0] += (double)b2f(u0.x); a0[1] += (double)b2f(u0.y);
            a0[2] += (double)b2f(u0.z); a0[3] += (double)b2f(u0.w);
            a1[0] += (double)b2f(u1.x); a1[1] += (double)b2f(u1.y);
            a1[2] += (double)b2f(u1.z); a1[3] += (double)b2f(u1.w);
        }
        if (j < je) {
            ushort4 u0 = *(const ushort4*)(msgd + (size_t)j * 32 + g * 4);
            a0[0] += (double)b2f(u0.x); a0[1] += (double)b2f(u0.y);
            a0[2] += (double)b2f(u0.z); a0[3] += (double)b2f(u0.w);
        }
        part[t] = a0 + a1;
    }
    __syncthreads();
    if (t < 64) {
        int m = t >> 3, g = t & 7;
        f64x4 v = part[m * 32 + g * 4] + part[m * 32 + g * 4 + 1] +
                  part[m * 32 + g * 4 + 2] + part[m * 32 + g * 4 + 3];
        int n = blockIdx.x * 8 + m;
        float2 agA = *(const float2*)(agg + (size_t)n * 32 + 2 * g);
        float2 agB = *(const float2*)(agg + (size_t)n * 32 + 16 + 2 * g);
        float r0 = (float)(v[0] + (double)agA.x);  // c = 2g
        float r2 = (float)(v[2] + (double)agA.y);  // c = 2g+1
        float r1 = (float)(v[1] + (double)agB.x);  // c = 2g+16
        float r3 = (float)(v[3] + (double)agB.y);  // c = 2g+17
        xs[m * 32 + 2 * g]      = r0 > 0.f ? r0 : 0.f;
        xs[m * 32 + 2 * g + 1]  = r2 > 0.f ? r2 : 0.f;
        xs[m * 32 + 2 * g + 16] = r1 > 0.f ? r1 : 0.f;
        xs[m * 32 + 2 * g + 17] = r3 > 0.f ? r3 : 0.f;
    }
    __syncthreads();
    if (t < 8) {
        int nn = blockIdx.x * 8 + t;
        float l0 = fcb[0], l1 = fcb[1], l2 = fcb[2], l3 = fcb[3];
#pragma unroll
        for (int oo = 0; oo < 32; ++oo) {
            float xv = xs[t * 32 + oo];
            l0 += xv * fcw[oo * 4 + 0];
            l1 += xv * fcw[oo * 4 + 1];
            l2 += xv * fcw[oo * 4 + 2];
            l3 += xv * fcw[oo * 4 + 3];
        }
        float mx = fmaxf(fmaxf(l0, l1), fmaxf(l2, l3));
        float s = expf(l0 - mx) + expf(l1 - mx) + expf(l2 - mx) + expf(l3 - mx);
        float lse = mx + logf(s);
        out[(size_t)nn * 4 + 0] = l0 - lse;
        out[(size_t)nn * 4 + 1] = l1 - lse;
        out[(size_t)nn * 4 + 2] = l2 - lse;
        out[(size_t)nn * 4 + 3] = l3 - lse;
    }
}

extern "C" void kernel_launch(void* const* d_in, const int* in_sizes, int n_in,
                              void* d_out, int out_size, void* d_ws, size_t ws_size,
                              hipStream_t stream) {
    const float* x0 = (const float*)d_in[0];
    const int*   ei = (const int*)d_in[1];
    const float* ea = (const float*)d_in[2];
    const float *W1[3], *B1[3], *W2[3], *B2[3], *RT[3], *BS[3];
    for (int l = 0; l < 3; ++l) {
        W1[l] = (const float*)d_in[3 + 6 * l];
        B1[l] = (const float*)d_in[4 + 6 * l];
        W2[l] = (const float*)d_in[5 + 6 * l];
        B2[l] = (const float*)d_in[6 + 6 * l];
        RT[l] = (const float*)d_in[7 + 6 * l];
        BS[l] = (const float*)d_in[8 + 6 * l];
    }
    const float* fcw = (const float*)d_in[21];
    const float* fcb = (const float*)d_in[22];
    float* out = (float*)d_out;

    // ---- workspace layout (all segment starts 16B-aligned) ----
    int*   cnt     = (int*)d_ws;                      // 10240
    int*   cntd    = cnt + 10240;                     // 10240 (contiguous with cnt for zeroing)
    int*   cursor  = cntd + 10240;                    // 10240
    int*   cursord = cursor + 10240;                  // 10240
    int*   off     = cursord + 10240;                 // 10240 (10001 used)
    int*   dst_off = off + 10240;                     // 10240 (10001 used)
    int*   qmap    = dst_off + 10240;                 // 160000
    float* w2t0    = (float*)(qmap + 160000);         // 4096
    float* w2t1    = w2t0 + 4096;                     // 32768
    float* w2t2    = w2t1 + 32768;                    // 32768
    float* xb2     = w2t2 + 32768;                    // 320000
    float* aggA    = xb2 + 320000;                    // 320000
    float* aggB    = aggA + 320000;                   // 320000
    unsigned short* msgdA = (unsigned short*)(aggB + 320000); // 5,120,000 bf16 (E x 32, dst-sorted)
    unsigned short* msgdB = msgdA + 5120000;                  // 5,120,000 bf16 (double buffer)
    float* ea_s    = (float*)(msgdB + 5120000);       // 320,000 f32 (E x 2, src-sorted)
    unsigned short* Gb = (unsigned short*)(ea_s + 320000);    // 10,240,000 bf16

    const int gE256 = (N_EDGES + 255) / 256;   // 625
    const int gL    = N_NODES / 8;             // 1250

    // ---- preprocessing (4 launches) ----
    k_tw2z<<<352, 256, 0, stream>>>(W2[0], W2[1], W2[2], w2t0, w2t1, w2t2, cnt);
    k_hist2<<<gE256, 256, 0, stream>>>(ei, cnt, cntd);
    k_scan2<<<2, 256, 0, stream>>>(cnt, cntd, off, dst_off, cursor, cursord);
    k_scatter<<<gE256, 256, 0, stream>>>(ei, ea, cursor, cursord, qmap, ea_s);

    // ---- fused layers (3 launches) ----
    k_GE<4, true><<<gL, 256, 0, stream>>>(x0, dst_off, msgdB /*unused*/, w2t0, B2[0], RT[0], BS[0],
                                          off, qmap, ea_s, W1[0], B1[0], Gb, xb2, aggA, msgdA);
    k_GE<32, false><<<gL, 256, 0, stream>>>(aggA, dst_off, msgdA, w2t1, B2[1], RT[1], BS[1],
                                            off, qmap, ea_s, W1[1], B1[1], Gb, xb2, aggB, msgdB);
    k_GE<32, false><<<gL, 256, 0, stream>>>(aggB, dst_off, msgdB, w2t2, B2[2], RT[2], BS[2],
                                            off, qmap, ea_s, W1[2], B1[2], Gb, xb2, aggA, msgdA);

    // ---- head ----
    k_final<<<gL, 256, 0, stream>>>(aggA, dst_off, msgdA, fcw, fcb, out);
}